// Round 16
// baseline (182.810 us; speedup 1.0000x reference)
//
#include <hip/hip_runtime.h>
#include <hip/hip_bf16.h>

// Shapes (fixed for this problem)
#define S_LEN 2048
#define HIDDIM 2048
#define NH 16
#define NKV 4
#define HD 128
#define KVROW 1024   // KVb row = [K(512) | V(512)]
#define QKVN 3072    // fused projection width

typedef __attribute__((ext_vector_type(8))) short short8;
typedef __attribute__((ext_vector_type(8))) unsigned short ushort8;
typedef __attribute__((ext_vector_type(4))) unsigned short ushort4v;
typedef __attribute__((ext_vector_type(4))) float f32x4;

__device__ __forceinline__ unsigned short f2bf(float f) {
  union { float f; unsigned int u; } v; v.f = f;
  unsigned int r = (v.u + 0x7FFFu + ((v.u >> 16) & 1u)) >> 16;
  return (unsigned short)r;
}
__device__ __forceinline__ float bf2f(unsigned short h) {
  union { unsigned int u; float f; } v; v.u = ((unsigned int)h) << 16;
  return v.f;
}

// Async global->LDS 16B copy. dst wave-uniform (HW adds lane*16B); src per-lane.
__device__ __forceinline__ void gl2lds16(const unsigned short* src,
                                         unsigned short* dst) {
  __builtin_amdgcn_global_load_lds(
      (const __attribute__((address_space(1))) unsigned int*)src,
      (__attribute__((address_space(3))) unsigned int*)dst, 16, 0, 0);
}

// ---------------------------------------------------------------------------
// Weight transpose body: W[k][n] fp32 (stride Nsrc) -> Wt[n_off+n][k] bf16.
// ---------------------------------------------------------------------------
__device__ __forceinline__ void tw_body(
    const float* __restrict__ W, unsigned short* __restrict__ Wt,
    int Nsrc, int Kdst, int n_off, int bx, int by, int tid,
    unsigned short (*Ts)[72]) {
  const int n0 = bx * 64, k0 = by * 64;
  const int c2 = (tid & 31) * 2, rb = tid >> 5;
#pragma unroll
  for (int p = 0; p < 8; ++p) {
    int r = rb + p * 8;
    float2 v = *(const float2*)&W[(size_t)(k0 + r) * Nsrc + n0 + c2];
    Ts[c2][r] = f2bf(v.x);
    Ts[c2 + 1][r] = f2bf(v.y);
  }
  __syncthreads();
  const int n = tid >> 2, kq = (tid & 3) * 16;
  ushort8 w0 = *(const ushort8*)&Ts[n][kq];
  ushort8 w1 = *(const ushort8*)&Ts[n][kq + 8];
  size_t base = (size_t)(n_off + n0 + n) * Kdst + k0 + kq;
  *(ushort8*)&Wt[base] = w0;
  *(ushort8*)&Wt[base + 8] = w1;
}

// ---------------------------------------------------------------------------
// Fused prep: h2b (blocks 0..2047) + wq^T (2048..3071) + wk^T (3072..3327)
// + wv^T (3328..3583) + maskbits (3584).
// ---------------------------------------------------------------------------
__global__ __launch_bounds__(256) void prep_kernel(
    const float* __restrict__ H, unsigned short* __restrict__ Hb,
    const float* __restrict__ wq, const float* __restrict__ wk,
    const float* __restrict__ wv, unsigned short* __restrict__ WT1,
    const int* __restrict__ amask, unsigned* __restrict__ mb) {
  __shared__ unsigned short Ts[64][72];
  const int b = (int)blockIdx.x, tid = threadIdx.x;
  if (b < 2048) {
    int i = (b * 256 + tid) * 8;
    float4 a = *(const float4*)(H + i), c = *(const float4*)(H + i + 4);
    ushort8 r;
    r[0] = f2bf(a.x); r[1] = f2bf(a.y); r[2] = f2bf(a.z); r[3] = f2bf(a.w);
    r[4] = f2bf(c.x); r[5] = f2bf(c.y); r[6] = f2bf(c.z); r[7] = f2bf(c.w);
    *(ushort8*)(Hb + i) = r;
  } else if (b < 3072) {
    int t = b - 2048;
    tw_body(wq, WT1, HIDDIM, HIDDIM, 0, t & 31, t >> 5, tid, Ts);
  } else if (b < 3328) {
    int t = b - 3072;
    tw_body(wk, WT1, 512, HIDDIM, 2048, t & 7, t >> 3, tid, Ts);
  } else if (b < 3584) {
    int t = b - 3328;
    tw_body(wv, WT1, 512, HIDDIM, 2560, t & 7, t >> 3, tid, Ts);
  } else {
    if (tid < 64) {
      unsigned m = 0;
#pragma unroll
      for (int i = 0; i < 32; ++i) m |= (amask[tid * 32 + i] != 0 ? 1u : 0u) << i;
      mb[tid] = m;
    }
  }
}

// ---------------------------------------------------------------------------
// Standalone weight transpose (Wo^T, runs after attn).
// ---------------------------------------------------------------------------
__global__ __launch_bounds__(256) void transpose_w(
    const float* __restrict__ W, unsigned short* __restrict__ Wt,
    int Nsrc, int Kdst, int n_off) {
  __shared__ unsigned short Ts[64][72];
  tw_body(W, Wt, Nsrc, Kdst, n_off, (int)blockIdx.x, (int)blockIdx.y,
          (int)threadIdx.x, Ts);
}

// ---------------------------------------------------------------------------
// Fused transpose_v (blocks 0..255) + rope (256..767).
// ---------------------------------------------------------------------------
__global__ __launch_bounds__(256) void tvrope_kernel(
    unsigned short* __restrict__ Qb, unsigned short* __restrict__ KVb,
    unsigned short* __restrict__ Vt, const int* __restrict__ pos) {
  __shared__ unsigned short Ts[64][72];
  const int b = (int)blockIdx.x, tid = threadIdx.x;
  if (b < 256) {
    const int c0 = (b & 7) * 64, s0 = (b >> 3) * 64;
    const int sr = tid >> 2, cq = (tid & 3) * 16;
    ushort8 a = *(const ushort8*)&KVb[(size_t)(s0 + sr) * KVROW + 512 + c0 + cq];
    ushort8 c = *(const ushort8*)&KVb[(size_t)(s0 + sr) * KVROW + 512 + c0 + cq + 8];
#pragma unroll
    for (int j = 0; j < 8; ++j) { Ts[cq + j][sr] = a[j]; Ts[cq + 8 + j][sr] = c[j]; }
    __syncthreads();
    const int cc = tid >> 2, sq = (tid & 3) * 16;
    ushort8 w0 = *(const ushort8*)&Ts[cc][sq];
    ushort8 w1 = *(const ushort8*)&Ts[cc][sq + 8];
    *(ushort8*)&Vt[(size_t)(c0 + cc) * S_LEN + s0 + sq] = w0;
    *(ushort8*)&Vt[(size_t)(c0 + cc) * S_LEN + s0 + sq + 8] = w1;
  } else {
    int idx = (b - 256) * 256 + tid;
    int s = idx >> 6, j = idx & 63;
    float inv = exp2f(-0.2076205059304703f * (float)j);
    float ang = (float)pos[s] * inv;
    float sn, cs;
    __sincosf(ang, &sn, &cs);
    auto rot = [&](unsigned short* base) {
      unsigned* p = (unsigned*)base;
      unsigned v = *p;
      float x0 = bf2f((unsigned short)(v & 0xffff));
      float x1 = bf2f((unsigned short)(v >> 16));
      unsigned r = (unsigned)f2bf(x0 * cs - x1 * sn) |
                   ((unsigned)f2bf(x0 * sn + x1 * cs) << 16);
      *p = r;
    };
#pragma unroll
    for (int hh = 0; hh < NH; ++hh) rot(Qb + (size_t)s * HIDDIM + hh * HD + 2 * j);
#pragma unroll
    for (int hh = 0; hh < NKV; ++hh) rot(KVb + (size_t)s * KVROW + hh * HD + 2 * j);
  }
}

// ---------------------------------------------------------------------------
// MFMA GEMM (TN) v3 (unchanged from R13): BM=128, BN=64, BK=64,
// global_load_lds staging, LDS dbuf, one barrier/step, XOR-swizzled tiles.
// ---------------------------------------------------------------------------
template <bool CF>
__global__ __launch_bounds__(256) void gemm_tn(
    const unsigned short* __restrict__ A, const unsigned short* __restrict__ Bt,
    void* __restrict__ C1, void* __restrict__ C2,
    int M, int N, int K, int splitcol, int ld1, int ld2) {
  __shared__ unsigned short As[2][128 * 64];
  __shared__ unsigned short Bs[2][64 * 64];
  const int m0 = blockIdx.y * 128, n0 = blockIdx.x * 64;
  const int tid = threadIdx.x, wid = tid >> 6, lane = tid & 63;
  const int wr = wid >> 1, wc = wid & 1;
  const int lr = lane & 15, lg = lane >> 4;

  f32x4 acc[4][2];
#pragma unroll
  for (int m = 0; m < 4; ++m)
#pragma unroll
    for (int n = 0; n < 2; ++n) acc[m][n] = (f32x4){0.f, 0.f, 0.f, 0.f};

  const int srow = lane >> 3;
  const int scolb = (lane & 7) << 4;
  auto stage = [&](int k0, int b) {
#pragma unroll
    for (int j = 0; j < 4; ++j) {
      int row = wid * 32 + j * 8 + srow;
      int src = (scolb ^ ((row & 7) << 4)) >> 1;
      gl2lds16(A + (size_t)(m0 + row) * K + k0 + src,
               &As[b][(wid * 32 + j * 8) * 64]);
    }
#pragma unroll
    for (int j = 0; j < 2; ++j) {
      int row = wid * 16 + j * 8 + srow;
      int src = (scolb ^ ((row & 7) << 4)) >> 1;
      gl2lds16(Bt + (size_t)(n0 + row) * K + k0 + src,
               &Bs[b][(wid * 16 + j * 8) * 64]);
    }
  };

  stage(0, 0);
  int cur = 0;
  for (int k0 = 0; k0 < K; k0 += 64) {
    __syncthreads();
    if (k0 + 64 < K) stage(k0 + 64, cur ^ 1);
#pragma unroll
    for (int s = 0; s < 2; ++s) {
      short8 af[4], bfv[2];
#pragma unroll
      for (int m = 0; m < 4; ++m) {
        int row = wr * 64 + m * 16 + lr;
        int off = ((s * 64 + lg * 16) ^ ((row & 7) << 4)) >> 1;
        af[m] = *(const short8*)&As[cur][row * 64 + off];
      }
#pragma unroll
      for (int n = 0; n < 2; ++n) {
        int row = wc * 32 + n * 16 + lr;
        int off = ((s * 64 + lg * 16) ^ ((row & 7) << 4)) >> 1;
        bfv[n] = *(const short8*)&Bs[cur][row * 64 + off];
      }
#pragma unroll
      for (int m = 0; m < 4; ++m)
#pragma unroll
        for (int n = 0; n < 2; ++n)
          acc[m][n] = __builtin_amdgcn_mfma_f32_16x16x32_bf16(af[m], bfv[n], acc[m][n], 0, 0, 0);
    }
    cur ^= 1;
  }

#pragma unroll
  for (int m = 0; m < 4; ++m)
#pragma unroll
    for (int n = 0; n < 2; ++n)
#pragma unroll
      for (int r = 0; r < 4; ++r) {
        int row = m0 + wr * 64 + m * 16 + lg * 4 + r;
        int col = n0 + wc * 32 + n * 16 + lr;
        float v = acc[m][n][r];
        if (CF) ((float*)C1)[(size_t)row * ld1 + col] = v;
        else if (col < splitcol) ((unsigned short*)C1)[(size_t)row * ld1 + col] = f2bf(v);
        else ((unsigned short*)C2)[(size_t)row * ld2 + (col - splitcol)] = f2bf(v);
      }
}

// ---------------------------------------------------------------------------
// Flash attention v14: KVBLK=64 (one barrier + one stage round per 64 keys,
// two 32-key sub-steps sharing the buffers). 4 waves; wave = head x 32 q-rows
// (two 16-row sets a/b sharing K/V frags). P routed via per-wave Plds
// (same-wave write->read, proven faster than shfl exchange). Uniform-work
// chunked grid (512-key chunks), additive partials + combine. K tile
// [64][128] and V^T tile [128][64] both XOR-swizzled (^(row&7)<<4) via
// pre-swizzled global source, staged with global_load_lds.
// ---------------------------------------------------------------------------
__global__ __launch_bounds__(256) void attn_kernel(
    const unsigned short* __restrict__ Qb, const unsigned short* __restrict__ KVb,
    const unsigned short* __restrict__ VtG, const unsigned* __restrict__ mbits,
    unsigned short* __restrict__ Ob,
    unsigned short* __restrict__ Opart, float* __restrict__ Lpart, int nsplit) {
  const int x = (int)blockIdx.x;        // 0..255
  const int qt = 63 - (x >> 2);         // short chunks last
  const int c = x & 3;
  const int kvh = (int)blockIdx.y;
  const int nch = (qt >> 4) + 1;
  if (nsplit == 0) { if (c != 0) return; }
  else if (c >= nch) return;
  const int qb = qt * 32;
  int kbeg = 0, kend = qb + 32;
  bool partial = false;
  if (nsplit && nch > 1) {
    kbeg = c * 512;
    kend = min(kend, kbeg + 512);
    partial = true;
  }

  __shared__ unsigned short Klds[2][64 * 128];  // K[key][d], swizzled (32KB)
  __shared__ unsigned short Vlds[2][128 * 64];  // V^T[d][key], swizzled (32KB)
  __shared__ unsigned short Plds[4][32][40];    // per-wave P[q32][key] (10KB)
  const int tid = threadIdx.x, wid = tid >> 6, lane = tid & 63;
  const int lr = lane & 15, lg = lane >> 4;
  const int h = kvh * 4 + wid;                  // wave's head

  short8 qfa[4], qfb[4];
  {
    const unsigned short* qpa = Qb + (size_t)(qb + lr) * HIDDIM + h * HD;
    const unsigned short* qpb = Qb + (size_t)(qb + 16 + lr) * HIDDIM + h * HD;
#pragma unroll
    for (int cc = 0; cc < 4; ++cc) {
      qfa[cc] = *(const short8*)(qpa + cc * 32 + lg * 8);
      qfb[cc] = *(const short8*)(qpb + cc * 32 + lg * 8);
    }
  }
  f32x4 oa[8], ob[8];
#pragma unroll
  for (int cc = 0; cc < 8; ++cc) {
    oa[cc] = (f32x4){0.f, 0.f, 0.f, 0.f};
    ob[cc] = (f32x4){0.f, 0.f, 0.f, 0.f};
  }
  float lsa = 0.f, lsb = 0.f;

  const unsigned short* Vg = VtG + (size_t)(kvh * HD) * S_LEN;

  // K stage: wave wid -> key rows wid*16 + j*4 + (lane>>4), j=0..3 (256B rows)
  // V stage: wave wid -> d rows wid*32 + j*8 + (lane>>3), j=0..3 (128B rows)
  auto stage = [&](int kt, int b) {
#pragma unroll
    for (int j = 0; j < 4; ++j) {
      int krow = wid * 16 + j * 4 + (lane >> 4);
      int ksrc = ((((lane & 15) << 4) ^ ((krow & 7) << 4))) >> 1;
      gl2lds16(KVb + (size_t)(kt + krow) * KVROW + kvh * HD + ksrc,
               &Klds[b][(wid * 16 + j * 4) * 128]);
      int vrow = wid * 32 + j * 8 + (lane >> 3);
      int vsrc = ((((lane & 7) << 4) ^ ((vrow & 7) << 4))) >> 1;
      gl2lds16(Vg + (size_t)vrow * S_LEN + kt + vsrc,
               &Vlds[b][(wid * 32 + j * 8) * 64]);
    }
  };

  stage(kbeg, 0);

  const int qra = qb + lr, qrb = qb + 16 + lr;
  const float SCALE = 0.08838834764831845f;
  int cur = 0;

  for (int kt = kbeg; kt < kend; kt += 64) {
    __syncthreads();  // drains async stage into buf[cur]
    if (kt + 64 < kend) stage(kt + 64, cur ^ 1);

#pragma unroll
    for (int s = 0; s < 2; ++s) {
      const int kts = kt + s * 32;
      if (kts >= kend) break;

      f32x4 sa[2], sb[2];
#pragma unroll
      for (int t = 0; t < 2; ++t) {
        sa[t] = (f32x4){0.f, 0.f, 0.f, 0.f};
        sb[t] = (f32x4){0.f, 0.f, 0.f, 0.f};
      }
      const unsigned short* kbase = &Klds[cur][0];
      __builtin_amdgcn_s_setprio(1);
#pragma unroll
      for (int t = 0; t < 2; ++t)
#pragma unroll
        for (int cc = 0; cc < 4; ++cc) {
          int krow = s * 32 + t * 16 + lr;
          short8 kf = *(const short8*)(kbase + (krow << 7) +
                                       ((((cc << 6) + (lg << 4)) ^ ((krow & 7) << 4)) >> 1));
          sa[t] = __builtin_amdgcn_mfma_f32_16x16x32_bf16(kf, qfa[cc], sa[t], 0, 0, 0);
          sb[t] = __builtin_amdgcn_mfma_f32_16x16x32_bf16(kf, qfb[cc], sb[t], 0, 0, 0);
        }
      __builtin_amdgcn_s_setprio(0);
      const unsigned mw = mbits[kts >> 5];
      float pa[2][4], pb[2][4];
      if ((kts + 31 <= qb) && (mw == ~0u)) {
#pragma unroll
        for (int t = 0; t < 2; ++t)
#pragma unroll
          for (int r = 0; r < 4; ++r) {
            float va = __expf(sa[t][r] * SCALE - 3.0f);
            float vb = __expf(sb[t][r] * SCALE - 3.0f);
            pa[t][r] = va; lsa += va;
            pb[t][r] = vb; lsb += vb;
          }
      } else {
#pragma unroll
        for (int t = 0; t < 2; ++t)
#pragma unroll
          for (int r = 0; r < 4; ++r) {
            int kk = t * 16 + lg * 4 + r;
            bool okm = (mw >> kk) & 1u;
            float va = __expf((okm && kts + kk <= qra) ? sa[t][r] * SCALE - 3.0f : -1e30f);
            float vb = __expf((okm && kts + kk <= qrb) ? sb[t][r] * SCALE - 3.0f : -1e30f);
            pa[t][r] = va; lsa += va;
            pb[t][r] = vb; lsb += vb;
          }
      }
#pragma unroll
      for (int t = 0; t < 2; ++t) {
        ushort4v pka, pkb;
#pragma unroll
        for (int r = 0; r < 4; ++r) { pka[r] = f2bf(pa[t][r]); pkb[r] = f2bf(pb[t][r]); }
        *(ushort4v*)&Plds[wid][lr][t * 16 + lg * 4] = pka;
        *(ushort4v*)&Plds[wid][16 + lr][t * 16 + lg * 4] = pkb;
      }
      short8 pfa = *(const short8*)&Plds[wid][lr][lg * 8];
      short8 pfb = *(const short8*)&Plds[wid][16 + lr][lg * 8];
      const unsigned short* vbase = &Vlds[cur][0];
      __builtin_amdgcn_s_setprio(1);
#pragma unroll
      for (int cc = 0; cc < 8; ++cc) {
        int vrow = cc * 16 + lr;
        short8 vf = *(const short8*)(vbase + (vrow << 6) +
                                     (((s * 64 + (lg << 4)) ^ ((vrow & 7) << 4)) >> 1));
        oa[cc] = __builtin_amdgcn_mfma_f32_16x16x32_bf16(pfa, vf, oa[cc], 0, 0, 0);
        ob[cc] = __builtin_amdgcn_mfma_f32_16x16x32_bf16(pfb, vf, ob[cc], 0, 0, 0);
      }
      __builtin_amdgcn_s_setprio(0);
    }
    cur ^= 1;
  }

  float la = lsa;
  la += __shfl_xor(la, 16, 64);
  la += __shfl_xor(la, 32, 64);
  float lb = lsb;
  lb += __shfl_xor(lb, 16, 64);
  lb += __shfl_xor(lb, 32, 64);

  if (!partial) {
    float lra[4], lrb[4];
#pragma unroll
    for (int r = 0; r < 4; ++r) {
      lra[r] = 1.0f / __shfl(la, lg * 4 + r, 16);
      lrb[r] = 1.0f / __shfl(lb, lg * 4 + r, 16);
    }
#pragma unroll
    for (int cc = 0; cc < 8; ++cc)
#pragma unroll
      for (int r = 0; r < 4; ++r) {
        const int rowa = qb + lg * 4 + r;
        const int rowb = qb + 16 + lg * 4 + r;
        Ob[(size_t)rowa * HIDDIM + h * HD + cc * 16 + lr] = f2bf(oa[cc][r] * lra[r]);
        Ob[(size_t)rowb * HIDDIM + h * HD + cc * 16 + lr] = f2bf(ob[cc][r] * lrb[r]);
      }
  } else {
    const int g = qt >> 4, j = qt & 15;
    const int base = (g == 1) ? 0 : (g == 2) ? 32 : 80;
    const int slot = base + j * nch + c + 144 * kvh;
    if (lg == 0) {
      Lpart[slot * 128 + wid * 32 + lr] = la;
      Lpart[slot * 128 + wid * 32 + 16 + lr] = lb;
    }
#pragma unroll
    for (int cc = 0; cc < 8; ++cc)
#pragma unroll
      for (int r = 0; r < 4; ++r) {
        Opart[(size_t)slot * 16384 + wid * 4096 +
              (lg * 4 + r) * 128 + cc * 16 + lr] = f2bf(oa[cc][r]);
        Opart[(size_t)slot * 16384 + wid * 4096 +
              (16 + lg * 4 + r) * 128 + cc * 16 + lr] = f2bf(ob[cc][r]);
      }
  }
}

// ---------------------------------------------------------------------------
__global__ __launch_bounds__(256) void combine_kernel(
    const unsigned short* __restrict__ Opart, const float* __restrict__ Lpart,
    unsigned short* __restrict__ Ab) {
  const int qt = 16 + (int)blockIdx.x;
  const int kvh = (int)blockIdx.y;
  const int nch = (qt >> 4) + 1;
  const int g = qt >> 4, j = qt & 15;
  const int base = (g == 1) ? 0 : (g == 2) ? 32 : 80;
  const int s0 = base + j * nch + 144 * kvh;
  const int tid = threadIdx.x;
  const int rowid = tid >> 1;
  const int d0 = (tid & 1) * 64;
  float L = 0.f;
  for (int cc = 0; cc < nch; ++cc) L += Lpart[(s0 + cc) * 128 + rowid];
  const float linv = 1.0f / L;
  const int h = kvh * 4 + (rowid >> 5);
  const int row = qt * 32 + (rowid & 31);
  unsigned short* dst = Ab + (size_t)row * HIDDIM + h * HD + d0;
  for (int i = 0; i < 64; i += 8) {
    float acc[8] = {0, 0, 0, 0, 0, 0, 0, 0};
    for (int cc = 0; cc < nch; ++cc) {
      ushort8 v = *(const ushort8*)&Opart[(size_t)(s0 + cc) * 16384 +
                                          rowid * 128 + d0 + i];
#pragma unroll
      for (int k = 0; k < 8; ++k) acc[k] += bf2f(v[k]);
    }
    ushort8 r;
#pragma unroll
    for (int k = 0; k < 8; ++k) r[k] = f2bf(acc[k] * linv);
    *(ushort8*)(dst + i) = r;
  }
}

// ---------------------------------------------------------------------------
extern "C" void kernel_launch(void* const* d_in, const int* in_sizes, int n_in,
                              void* d_out, int out_size, void* d_ws, size_t ws_size,
                              hipStream_t stream) {
  const float* hidden = (const float*)d_in[0];
  const float* wq = (const float*)d_in[1];
  const float* wk = (const float*)d_in[2];
  const float* wv = (const float*)d_in[3];
  const float* wo = (const float*)d_in[4];
  const int* amask = (const int*)d_in[5];
  const int* pos = (const int*)d_in[6];

  unsigned short* Qb = (unsigned short*)d_ws;              // 0      .. 8.39MB
  unsigned short* KVb = Qb + (size_t)S_LEN * HIDDIM;       // 8.39   .. 12.58
  unsigned short* Ab = KVb + (size_t)S_LEN * KVROW;        // 12.58  .. 20.97
  unsigned short* WT1 = Ab + (size_t)S_LEN * HIDDIM;       // 20.97  .. 33.55
  unsigned short* Hb = WT1 + (size_t)QKVN * HIDDIM;        // 33.55  .. 41.94
  float* out = (float*)d_out;

  // Chunked-path extras (aliasing WT1+Hb, dead during attn):
  unsigned short* Opart = WT1;                             // 576 slots x 32KB
  unsigned short* Vt_chunk = WT1 + (size_t)576 * 16384;
  unsigned* mbits_chunk = (unsigned*)((char*)d_ws + 41943040ull);
  float* Lpart = (float*)((char*)d_ws + 41943296ull);
  const size_t need_chunk = 42238208ull;
  // Fallback locations:
  unsigned short* Vt_fb = WT1 + (size_t)HIDDIM * HIDDIM;
  unsigned* mbits_fb = (unsigned*)((char*)d_ws + 31457280ull);

  const int nsplit = (ws_size >= need_chunk) ? 1 : 0;
  unsigned short* Vt = nsplit ? Vt_chunk : Vt_fb;
  unsigned* mbits = nsplit ? mbits_chunk : mbits_fb;

  dim3 blk(256);
  // Fused prep: h2b + wq/wk/wv transposes + maskbits
  prep_kernel<<<3585, blk, 0, stream>>>(hidden, Hb, wq, wk, wv, WT1, amask, mbits);
  // Fused QKV projection: cols<2048 -> Qb, else -> KVb
  gemm_tn<false><<<dim3(QKVN / 64, S_LEN / 128), blk, 0, stream>>>(
      Hb, WT1, Qb, KVb, S_LEN, QKVN, HIDDIM, 2048, HIDDIM, KVROW);
  // Fused V transpose + RoPE
  tvrope_kernel<<<768, blk, 0, stream>>>(Qb, KVb, Vt, pos);
  // Attention: uniform-work chunked grid, 4-wave blocks, KVBLK=64
  attn_kernel<<<dim3(256, NKV), blk, 0, stream>>>(
      Qb, KVb, Vt, mbits, Ab, Opart, Lpart, nsplit);
  if (nsplit)
    combine_kernel<<<dim3(48, NKV), blk, 0, stream>>>(Opart, Lpart, Ab);
  // Wo^T AFTER attn/combine (it overwrites the Opart region)
  transpose_w<<<dim3(32, 32), blk, 0, stream>>>(wo, WT1, HIDDIM, HIDDIM, 0);
  // Output projection (fp32 out)
  gemm_tn<true><<<dim3(HIDDIM / 64, S_LEN / 128), blk, 0, stream>>>(
      Ab, WT1, out, nullptr, S_LEN, HIDDIM, HIDDIM, HIDDIM, HIDDIM, 0);
}

// Round 17
// 155.094 us; speedup vs baseline: 1.1787x; 1.1787x over previous
//
#include <hip/hip_runtime.h>
#include <hip/hip_bf16.h>

// Shapes (fixed for this problem)
#define S_LEN 2048
#define HIDDIM 2048
#define NH 16
#define NKV 4
#define HD 128
#define KVROW 1024   // KVb row = [K(512) | V(512)]
#define QKVN 3072    // fused projection width

typedef __attribute__((ext_vector_type(8))) short short8;
typedef __attribute__((ext_vector_type(8))) unsigned short ushort8;
typedef __attribute__((ext_vector_type(4))) unsigned short ushort4v;
typedef __attribute__((ext_vector_type(4))) float f32x4;

__device__ __forceinline__ unsigned short f2bf(float f) {
  union { float f; unsigned int u; } v; v.f = f;
  unsigned int r = (v.u + 0x7FFFu + ((v.u >> 16) & 1u)) >> 16;
  return (unsigned short)r;
}
__device__ __forceinline__ float bf2f(unsigned short h) {
  union { unsigned int u; float f; } v; v.u = ((unsigned int)h) << 16;
  return v.f;
}

// Async global->LDS 16B copy. dst wave-uniform (HW adds lane*16B); src per-lane.
__device__ __forceinline__ void gl2lds16(const unsigned short* src,
                                         unsigned short* dst) {
  __builtin_amdgcn_global_load_lds(
      (const __attribute__((address_space(1))) unsigned int*)src,
      (__attribute__((address_space(3))) unsigned int*)dst, 16, 0, 0);
}

// ---------------------------------------------------------------------------
// Weight transpose body: W[k][n] fp32 (stride Nsrc) -> Wt[n_off+n][k] bf16.
// ---------------------------------------------------------------------------
__device__ __forceinline__ void tw_body(
    const float* __restrict__ W, unsigned short* __restrict__ Wt,
    int Nsrc, int Kdst, int n_off, int bx, int by, int tid,
    unsigned short (*Ts)[72]) {
  const int n0 = bx * 64, k0 = by * 64;
  const int c2 = (tid & 31) * 2, rb = tid >> 5;
#pragma unroll
  for (int p = 0; p < 8; ++p) {
    int r = rb + p * 8;
    float2 v = *(const float2*)&W[(size_t)(k0 + r) * Nsrc + n0 + c2];
    Ts[c2][r] = f2bf(v.x);
    Ts[c2 + 1][r] = f2bf(v.y);
  }
  __syncthreads();
  const int n = tid >> 2, kq = (tid & 3) * 16;
  ushort8 w0 = *(const ushort8*)&Ts[n][kq];
  ushort8 w1 = *(const ushort8*)&Ts[n][kq + 8];
  size_t base = (size_t)(n_off + n0 + n) * Kdst + k0 + kq;
  *(ushort8*)&Wt[base] = w0;
  *(ushort8*)&Wt[base + 8] = w1;
}

// ---------------------------------------------------------------------------
// Fused prep: h2b (blocks 0..2047) + wq^T (2048..3071) + wk^T (3072..3327)
// + wv^T (3328..3583) [+ wo^T (3584..4607) when tier2].
// ---------------------------------------------------------------------------
__global__ __launch_bounds__(256) void prep_kernel(
    const float* __restrict__ H, unsigned short* __restrict__ Hb,
    const float* __restrict__ wq, const float* __restrict__ wk,
    const float* __restrict__ wv, unsigned short* __restrict__ WT1,
    const float* __restrict__ wo, unsigned short* __restrict__ WoT) {
  __shared__ unsigned short Ts[64][72];
  const int b = (int)blockIdx.x, tid = threadIdx.x;
  if (b < 2048) {
    int i = (b * 256 + tid) * 8;
    float4 a = *(const float4*)(H + i), c = *(const float4*)(H + i + 4);
    ushort8 r;
    r[0] = f2bf(a.x); r[1] = f2bf(a.y); r[2] = f2bf(a.z); r[3] = f2bf(a.w);
    r[4] = f2bf(c.x); r[5] = f2bf(c.y); r[6] = f2bf(c.z); r[7] = f2bf(c.w);
    *(ushort8*)(Hb + i) = r;
  } else if (b < 3072) {
    int t = b - 2048;
    tw_body(wq, WT1, HIDDIM, HIDDIM, 0, t & 31, t >> 5, tid, Ts);
  } else if (b < 3328) {
    int t = b - 3072;
    tw_body(wk, WT1, 512, HIDDIM, 2048, t & 7, t >> 3, tid, Ts);
  } else if (b < 3584) {
    int t = b - 3328;
    tw_body(wv, WT1, 512, HIDDIM, 2560, t & 7, t >> 3, tid, Ts);
  } else {
    int t = b - 3584;
    tw_body(wo, WoT, HIDDIM, HIDDIM, 0, t & 31, t >> 5, tid, Ts);
  }
}

// ---------------------------------------------------------------------------
// Standalone weight transpose (Wo^T fallback path, runs after attn).
// ---------------------------------------------------------------------------
__global__ __launch_bounds__(256) void transpose_w(
    const float* __restrict__ W, unsigned short* __restrict__ Wt,
    int Nsrc, int Kdst, int n_off) {
  __shared__ unsigned short Ts[64][72];
  tw_body(W, Wt, Nsrc, Kdst, n_off, (int)blockIdx.x, (int)blockIdx.y,
          (int)threadIdx.x, Ts);
}

// ---------------------------------------------------------------------------
// Fused transpose_v (blocks 0..255) + rope (256..767) + maskbits (768).
// ---------------------------------------------------------------------------
__global__ __launch_bounds__(256) void tvrope_kernel(
    unsigned short* __restrict__ Qb, unsigned short* __restrict__ KVb,
    unsigned short* __restrict__ Vt, const int* __restrict__ pos,
    const int* __restrict__ amask, unsigned* __restrict__ mb) {
  __shared__ unsigned short Ts[64][72];
  const int b = (int)blockIdx.x, tid = threadIdx.x;
  if (b < 256) {
    const int c0 = (b & 7) * 64, s0 = (b >> 3) * 64;
    const int sr = tid >> 2, cq = (tid & 3) * 16;
    ushort8 a = *(const ushort8*)&KVb[(size_t)(s0 + sr) * KVROW + 512 + c0 + cq];
    ushort8 c = *(const ushort8*)&KVb[(size_t)(s0 + sr) * KVROW + 512 + c0 + cq + 8];
#pragma unroll
    for (int j = 0; j < 8; ++j) { Ts[cq + j][sr] = a[j]; Ts[cq + 8 + j][sr] = c[j]; }
    __syncthreads();
    const int cc = tid >> 2, sq = (tid & 3) * 16;
    ushort8 w0 = *(const ushort8*)&Ts[cc][sq];
    ushort8 w1 = *(const ushort8*)&Ts[cc][sq + 8];
    *(ushort8*)&Vt[(size_t)(c0 + cc) * S_LEN + s0 + sq] = w0;
    *(ushort8*)&Vt[(size_t)(c0 + cc) * S_LEN + s0 + sq + 8] = w1;
  } else if (b < 768) {
    int idx = (b - 256) * 256 + tid;
    int s = idx >> 6, j = idx & 63;
    float inv = exp2f(-0.2076205059304703f * (float)j);
    float ang = (float)pos[s] * inv;
    float sn, cs;
    __sincosf(ang, &sn, &cs);
    auto rot = [&](unsigned short* base) {
      unsigned* p = (unsigned*)base;
      unsigned v = *p;
      float x0 = bf2f((unsigned short)(v & 0xffff));
      float x1 = bf2f((unsigned short)(v >> 16));
      unsigned r = (unsigned)f2bf(x0 * cs - x1 * sn) |
                   ((unsigned)f2bf(x0 * sn + x1 * cs) << 16);
      *p = r;
    };
#pragma unroll
    for (int hh = 0; hh < NH; ++hh) rot(Qb + (size_t)s * HIDDIM + hh * HD + 2 * j);
#pragma unroll
    for (int hh = 0; hh < NKV; ++hh) rot(KVb + (size_t)s * KVROW + hh * HD + 2 * j);
  } else {
    if (tid < 64) {
      unsigned m = 0;
#pragma unroll
      for (int i = 0; i < 32; ++i) m |= (amask[tid * 32 + i] != 0 ? 1u : 0u) << i;
      mb[tid] = m;
    }
  }
}

// ---------------------------------------------------------------------------
// MFMA GEMM (TN) v3 (unchanged from R13): BM=128, BN=64, BK=64,
// global_load_lds staging, LDS dbuf, one barrier/step, XOR-swizzled tiles.
// ---------------------------------------------------------------------------
template <bool CF>
__global__ __launch_bounds__(256) void gemm_tn(
    const unsigned short* __restrict__ A, const unsigned short* __restrict__ Bt,
    void* __restrict__ C1, void* __restrict__ C2,
    int M, int N, int K, int splitcol, int ld1, int ld2) {
  __shared__ unsigned short As[2][128 * 64];
  __shared__ unsigned short Bs[2][64 * 64];
  const int m0 = blockIdx.y * 128, n0 = blockIdx.x * 64;
  const int tid = threadIdx.x, wid = tid >> 6, lane = tid & 63;
  const int wr = wid >> 1, wc = wid & 1;
  const int lr = lane & 15, lg = lane >> 4;

  f32x4 acc[4][2];
#pragma unroll
  for (int m = 0; m < 4; ++m)
#pragma unroll
    for (int n = 0; n < 2; ++n) acc[m][n] = (f32x4){0.f, 0.f, 0.f, 0.f};

  const int srow = lane >> 3;
  const int scolb = (lane & 7) << 4;
  auto stage = [&](int k0, int b) {
#pragma unroll
    for (int j = 0; j < 4; ++j) {
      int row = wid * 32 + j * 8 + srow;
      int src = (scolb ^ ((row & 7) << 4)) >> 1;
      gl2lds16(A + (size_t)(m0 + row) * K + k0 + src,
               &As[b][(wid * 32 + j * 8) * 64]);
    }
#pragma unroll
    for (int j = 0; j < 2; ++j) {
      int row = wid * 16 + j * 8 + srow;
      int src = (scolb ^ ((row & 7) << 4)) >> 1;
      gl2lds16(Bt + (size_t)(n0 + row) * K + k0 + src,
               &Bs[b][(wid * 16 + j * 8) * 64]);
    }
  };

  stage(0, 0);
  int cur = 0;
  for (int k0 = 0; k0 < K; k0 += 64) {
    __syncthreads();
    if (k0 + 64 < K) stage(k0 + 64, cur ^ 1);
#pragma unroll
    for (int s = 0; s < 2; ++s) {
      short8 af[4], bfv[2];
#pragma unroll
      for (int m = 0; m < 4; ++m) {
        int row = wr * 64 + m * 16 + lr;
        int off = ((s * 64 + lg * 16) ^ ((row & 7) << 4)) >> 1;
        af[m] = *(const short8*)&As[cur][row * 64 + off];
      }
#pragma unroll
      for (int n = 0; n < 2; ++n) {
        int row = wc * 32 + n * 16 + lr;
        int off = ((s * 64 + lg * 16) ^ ((row & 7) << 4)) >> 1;
        bfv[n] = *(const short8*)&Bs[cur][row * 64 + off];
      }
#pragma unroll
      for (int m = 0; m < 4; ++m)
#pragma unroll
        for (int n = 0; n < 2; ++n)
          acc[m][n] = __builtin_amdgcn_mfma_f32_16x16x32_bf16(af[m], bfv[n], acc[m][n], 0, 0, 0);
    }
    cur ^= 1;
  }

#pragma unroll
  for (int m = 0; m < 4; ++m)
#pragma unroll
    for (int n = 0; n < 2; ++n)
#pragma unroll
      for (int r = 0; r < 4; ++r) {
        int row = m0 + wr * 64 + m * 16 + lg * 4 + r;
        int col = n0 + wc * 32 + n * 16 + lr;
        float v = acc[m][n][r];
        if (CF) ((float*)C1)[(size_t)row * ld1 + col] = v;
        else if (col < splitcol) ((unsigned short*)C1)[(size_t)row * ld1 + col] = f2bf(v);
        else ((unsigned short*)C2)[(size_t)row * ld2 + (col - splitcol)] = f2bf(v);
      }
}

// ---------------------------------------------------------------------------
// Flash attention v12 (R14 verbatim — measured best at 59.9us): uniform-work
// chunked grid; block = 4 waves x 256 thr; wave = 1 head x 32 q-rows (two
// 16-row MFMA sets a/b sharing every K/V fragment). KVBLK=32, Plds P-path,
// global_load_lds staging with XOR swizzles, uniform fast-path on interior.
// ---------------------------------------------------------------------------
__global__ __launch_bounds__(256) void attn_kernel(
    const unsigned short* __restrict__ Qb, const unsigned short* __restrict__ KVb,
    const unsigned short* __restrict__ VtG, const unsigned* __restrict__ mbits,
    unsigned short* __restrict__ Ob,
    unsigned short* __restrict__ Opart, float* __restrict__ Lpart, int nsplit) {
  const int x = (int)blockIdx.x;        // 0..255
  const int qt = 63 - (x >> 2);         // short chunks last
  const int c = x & 3;
  const int kvh = (int)blockIdx.y;
  const int nch = (qt >> 4) + 1;
  if (nsplit == 0) { if (c != 0) return; }
  else if (c >= nch) return;
  const int qb = qt * 32;
  int kbeg = 0, kend = qb + 32;
  bool partial = false;
  if (nsplit && nch > 1) {
    kbeg = c * 512;
    kend = min(kend, kbeg + 512);
    partial = true;
  }

  __shared__ unsigned short Klds[2][32 * 128];  // K[key][d], swizzled
  __shared__ unsigned short Vlds[2][128 * 32];  // V^T[d][key], swizzled
  __shared__ unsigned short Plds[4][32][40];    // per-wave P[q32][key]
  const int tid = threadIdx.x, wid = tid >> 6, lane = tid & 63;
  const int lr = lane & 15, lg = lane >> 4;
  const int h = kvh * 4 + wid;                  // wave's head

  short8 qfa[4], qfb[4];
  {
    const unsigned short* qpa = Qb + (size_t)(qb + lr) * HIDDIM + h * HD;
    const unsigned short* qpb = Qb + (size_t)(qb + 16 + lr) * HIDDIM + h * HD;
#pragma unroll
    for (int cc = 0; cc < 4; ++cc) {
      qfa[cc] = *(const short8*)(qpa + cc * 32 + lg * 8);
      qfb[cc] = *(const short8*)(qpb + cc * 32 + lg * 8);
    }
  }
  f32x4 oa[8], ob[8];
#pragma unroll
  for (int cc = 0; cc < 8; ++cc) {
    oa[cc] = (f32x4){0.f, 0.f, 0.f, 0.f};
    ob[cc] = (f32x4){0.f, 0.f, 0.f, 0.f};
  }
  float lsa = 0.f, lsb = 0.f;

  const unsigned short* Vg = VtG + (size_t)(kvh * HD) * S_LEN;

  const int ksr_ = lane >> 4;
  const int kscb = (lane & 15) << 4;
  const int vsr_ = lane >> 2;
  const int vscb = (lane & 3) << 4;

  auto stage = [&](int kt, int b) {
#pragma unroll
    for (int j = 0; j < 2; ++j) {
      int krow = wid * 8 + j * 4 + ksr_;
      int ksrc = (kscb ^ ((krow & 7) << 4)) >> 1;
      gl2lds16(KVb + (size_t)(kt + krow) * KVROW + kvh * HD + ksrc,
               &Klds[b][(wid * 8 + j * 4) * 128]);
      int vrow = wid * 32 + j * 16 + vsr_;
      int vsrc = (vscb ^ ((vrow & 3) << 4)) >> 1;
      gl2lds16(Vg + (size_t)vrow * S_LEN + kt + vsrc,
               &Vlds[b][(wid * 32 + j * 16) * 32]);
    }
  };

  stage(kbeg, 0);

  const int qra = qb + lr, qrb = qb + 16 + lr;
  const float SCALE = 0.08838834764831845f;
  int cur = 0;

  for (int kt = kbeg; kt < kend; kt += 32) {
    __syncthreads();  // drains async stage into buf[cur]
    if (kt + 32 < kend) stage(kt + 32, cur ^ 1);

    f32x4 sa[2], sb[2];
#pragma unroll
    for (int t = 0; t < 2; ++t) {
      sa[t] = (f32x4){0.f, 0.f, 0.f, 0.f};
      sb[t] = (f32x4){0.f, 0.f, 0.f, 0.f};
    }
    const unsigned short* kbase = &Klds[cur][0];
    __builtin_amdgcn_s_setprio(1);
#pragma unroll
    for (int t = 0; t < 2; ++t)
#pragma unroll
      for (int cc = 0; cc < 4; ++cc) {
        short8 kf = *(const short8*)(kbase + ((t * 16 + lr) << 7) +
                                     ((((cc << 6) + (lg << 4)) ^ ((lr & 7) << 4)) >> 1));
        sa[t] = __builtin_amdgcn_mfma_f32_16x16x32_bf16(kf, qfa[cc], sa[t], 0, 0, 0);
        sb[t] = __builtin_amdgcn_mfma_f32_16x16x32_bf16(kf, qfb[cc], sb[t], 0, 0, 0);
      }
    __builtin_amdgcn_s_setprio(0);
    const unsigned mw = mbits[kt >> 5];
    float pa[2][4], pb[2][4];
    if ((kt + 31 <= qb) && (mw == ~0u)) {
#pragma unroll
      for (int t = 0; t < 2; ++t)
#pragma unroll
        for (int r = 0; r < 4; ++r) {
          float va = __expf(sa[t][r] * SCALE - 3.0f);
          float vb = __expf(sb[t][r] * SCALE - 3.0f);
          pa[t][r] = va; lsa += va;
          pb[t][r] = vb; lsb += vb;
        }
    } else {
#pragma unroll
      for (int t = 0; t < 2; ++t)
#pragma unroll
        for (int r = 0; r < 4; ++r) {
          int kk = t * 16 + lg * 4 + r;
          bool okm = (mw >> kk) & 1u;
          float va = __expf((okm && kt + kk <= qra) ? sa[t][r] * SCALE - 3.0f : -1e30f);
          float vb = __expf((okm && kt + kk <= qrb) ? sb[t][r] * SCALE - 3.0f : -1e30f);
          pa[t][r] = va; lsa += va;
          pb[t][r] = vb; lsb += vb;
        }
    }
#pragma unroll
    for (int t = 0; t < 2; ++t) {
      ushort4v pka, pkb;
#pragma unroll
      for (int r = 0; r < 4; ++r) { pka[r] = f2bf(pa[t][r]); pkb[r] = f2bf(pb[t][r]); }
      *(ushort4v*)&Plds[wid][lr][t * 16 + lg * 4] = pka;
      *(ushort4v*)&Plds[wid][16 + lr][t * 16 + lg * 4] = pkb;
    }
    short8 pfa = *(const short8*)&Plds[wid][lr][lg * 8];
    short8 pfb = *(const short8*)&Plds[wid][16 + lr][lg * 8];
    const unsigned short* vbase = &Vlds[cur][0];
    __builtin_amdgcn_s_setprio(1);
#pragma unroll
    for (int cc = 0; cc < 8; ++cc) {
      short8 vf = *(const short8*)(vbase + ((cc * 16 + lr) << 5) +
                                   ((lg ^ (lr & 3)) << 3));
      oa[cc] = __builtin_amdgcn_mfma_f32_16x16x32_bf16(pfa, vf, oa[cc], 0, 0, 0);
      ob[cc] = __builtin_amdgcn_mfma_f32_16x16x32_bf16(pfb, vf, ob[cc], 0, 0, 0);
    }
    __builtin_amdgcn_s_setprio(0);
    cur ^= 1;
  }

  float la = lsa;
  la += __shfl_xor(la, 16, 64);
  la += __shfl_xor(la, 32, 64);
  float lb = lsb;
  lb += __shfl_xor(lb, 16, 64);
  lb += __shfl_xor(lb, 32, 64);

  if (!partial) {
    float lra[4], lrb[4];
#pragma unroll
    for (int r = 0; r < 4; ++r) {
      lra[r] = 1.0f / __shfl(la, lg * 4 + r, 16);
      lrb[r] = 1.0f / __shfl(lb, lg * 4 + r, 16);
    }
#pragma unroll
    for (int cc = 0; cc < 8; ++cc)
#pragma unroll
      for (int r = 0; r < 4; ++r) {
        const int rowa = qb + lg * 4 + r;
        const int rowb = qb + 16 + lg * 4 + r;
        Ob[(size_t)rowa * HIDDIM + h * HD + cc * 16 + lr] = f2bf(oa[cc][r] * lra[r]);
        Ob[(size_t)rowb * HIDDIM + h * HD + cc * 16 + lr] = f2bf(ob[cc][r] * lrb[r]);
      }
  } else {
    const int g = qt >> 4, j = qt & 15;
    const int base = (g == 1) ? 0 : (g == 2) ? 32 : 80;
    const int slot = base + j * nch + c + 144 * kvh;
    if (lg == 0) {
      Lpart[slot * 128 + wid * 32 + lr] = la;
      Lpart[slot * 128 + wid * 32 + 16 + lr] = lb;
    }
#pragma unroll
    for (int cc = 0; cc < 8; ++cc)
#pragma unroll
      for (int r = 0; r < 4; ++r) {
        Opart[(size_t)slot * 16384 + wid * 4096 +
              (lg * 4 + r) * 128 + cc * 16 + lr] = f2bf(oa[cc][r]);
        Opart[(size_t)slot * 16384 + wid * 4096 +
              (16 + lg * 4 + r) * 128 + cc * 16 + lr] = f2bf(ob[cc][r]);
      }
  }
}

// ---------------------------------------------------------------------------
__global__ __launch_bounds__(256) void combine_kernel(
    const unsigned short* __restrict__ Opart, const float* __restrict__ Lpart,
    unsigned short* __restrict__ Ab) {
  const int qt = 16 + (int)blockIdx.x;
  const int kvh = (int)blockIdx.y;
  const int nch = (qt >> 4) + 1;
  const int g = qt >> 4, j = qt & 15;
  const int base = (g == 1) ? 0 : (g == 2) ? 32 : 80;
  const int s0 = base + j * nch + 144 * kvh;
  const int tid = threadIdx.x;
  const int rowid = tid >> 1;
  const int d0 = (tid & 1) * 64;
  float L = 0.f;
  for (int cc = 0; cc < nch; ++cc) L += Lpart[(s0 + cc) * 128 + rowid];
  const float linv = 1.0f / L;
  const int h = kvh * 4 + (rowid >> 5);
  const int row = qt * 32 + (rowid & 31);
  unsigned short* dst = Ab + (size_t)row * HIDDIM + h * HD + d0;
  for (int i = 0; i < 64; i += 8) {
    float acc[8] = {0, 0, 0, 0, 0, 0, 0, 0};
    for (int cc = 0; cc < nch; ++cc) {
      ushort8 v = *(const ushort8*)&Opart[(size_t)(s0 + cc) * 16384 +
                                          rowid * 128 + d0 + i];
#pragma unroll
      for (int k = 0; k < 8; ++k) acc[k] += bf2f(v[k]);
    }
    ushort8 r;
#pragma unroll
    for (int k = 0; k < 8; ++k) r[k] = f2bf(acc[k] * linv);
    *(ushort8*)(dst + i) = r;
  }
}

// ---------------------------------------------------------------------------
extern "C" void kernel_launch(void* const* d_in, const int* in_sizes, int n_in,
                              void* d_out, int out_size, void* d_ws, size_t ws_size,
                              hipStream_t stream) {
  const float* hidden = (const float*)d_in[0];
  const float* wq = (const float*)d_in[1];
  const float* wk = (const float*)d_in[2];
  const float* wv = (const float*)d_in[3];
  const float* wo = (const float*)d_in[4];
  const int* amask = (const int*)d_in[5];
  const int* pos = (const int*)d_in[6];

  unsigned short* Qb = (unsigned short*)d_ws;              // 0      .. 8.39MB
  unsigned short* KVb = Qb + (size_t)S_LEN * HIDDIM;       // 8.39   .. 12.58
  unsigned short* Ab = KVb + (size_t)S_LEN * KVROW;        // 12.58  .. 20.97
  unsigned short* WT1 = Ab + (size_t)S_LEN * HIDDIM;       // 20.97  .. 33.55
  unsigned short* Hb = WT1 + (size_t)QKVN * HIDDIM;        // 33.55  .. 41.94
  float* out = (float*)d_out;

  // Chunked-path extras (aliasing WT1+Hb, dead during attn):
  unsigned short* Opart = WT1;                             // 576 slots x 32KB
  unsigned short* Vt_chunk = WT1 + (size_t)576 * 16384;
  unsigned* mbits_chunk = (unsigned*)((char*)d_ws + 41943040ull);
  float* Lpart = (float*)((char*)d_ws + 41943296ull);
  const size_t need_chunk = 42238208ull;
  // Tier2: separate Wo^T buffer (transposed early inside prep)
  unsigned short* WoT2 = (unsigned short*)((char*)d_ws + 42238208ull);
  const size_t need_tier2 = 42238208ull + 8388608ull;
  // Fallback locations:
  unsigned short* Vt_fb = WT1 + (size_t)HIDDIM * HIDDIM;
  unsigned* mbits_fb = (unsigned*)((char*)d_ws + 31457280ull);

  const int nsplit = (ws_size >= need_chunk) ? 1 : 0;
  const int tier2 = (ws_size >= need_tier2) ? 1 : 0;
  unsigned short* Vt = nsplit ? Vt_chunk : Vt_fb;
  unsigned* mbits = nsplit ? mbits_chunk : mbits_fb;
  unsigned short* WoT = tier2 ? WoT2 : WT1;

  dim3 blk(256);
  // Fused prep: h2b + wq/wk/wv transposes (+ wo^T when tier2)
  prep_kernel<<<tier2 ? 4608 : 3584, blk, 0, stream>>>(
      hidden, Hb, wq, wk, wv, WT1, wo, WoT2);
  // Fused QKV projection: cols<2048 -> Qb, else -> KVb
  gemm_tn<false><<<dim3(QKVN / 64, S_LEN / 128), blk, 0, stream>>>(
      Hb, WT1, Qb, KVb, S_LEN, QKVN, HIDDIM, 2048, HIDDIM, KVROW);
  // Fused V transpose + RoPE + maskbits
  tvrope_kernel<<<769, blk, 0, stream>>>(Qb, KVb, Vt, pos, amask, mbits);
  // Attention: uniform-work chunked grid, 4-wave blocks (R14 best)
  attn_kernel<<<dim3(256, NKV), blk, 0, stream>>>(
      Qb, KVb, Vt, mbits, Ab, Opart, Lpart, nsplit);
  if (nsplit)
    combine_kernel<<<dim3(48, NKV), blk, 0, stream>>>(Opart, Lpart, Ab);
  // Fallback only: Wo^T late into WT1 (tier2 already did it in prep)
  if (!tier2)
    transpose_w<<<dim3(32, 32), blk, 0, stream>>>(wo, WT1, HIDDIM, HIDDIM, 0);
  // Output projection (fp32 out)
  gemm_tn<true><<<dim3(HIDDIM / 64, S_LEN / 128), blk, 0, stream>>>(
      Ab, WoT, out, nullptr, S_LEN, HIDDIM, HIDDIM, HIDDIM, HIDDIM, 0);
}

// Round 18
// 152.748 us; speedup vs baseline: 1.1968x; 1.0154x over previous
//
#include <hip/hip_runtime.h>
#include <hip/hip_bf16.h>

// Shapes (fixed for this problem)
#define S_LEN 2048
#define HIDDIM 2048
#define NH 16
#define NKV 4
#define HD 128
#define KVROW 1024   // KVb row = [K(512) | V(512)]
#define QKVN 3072    // fused projection width

typedef __attribute__((ext_vector_type(8))) short short8;
typedef __attribute__((ext_vector_type(8))) unsigned short ushort8;
typedef __attribute__((ext_vector_type(4))) unsigned short ushort4v;
typedef __attribute__((ext_vector_type(4))) float f32x4;

__device__ __forceinline__ unsigned short f2bf(float f) {
  union { float f; unsigned int u; } v; v.f = f;
  unsigned int r = (v.u + 0x7FFFu + ((v.u >> 16) & 1u)) >> 16;
  return (unsigned short)r;
}
__device__ __forceinline__ float bf2f(unsigned short h) {
  union { unsigned int u; float f; } v; v.u = ((unsigned int)h) << 16;
  return v.f;
}

// Async global->LDS 16B copy. dst wave-uniform (HW adds lane*16B); src per-lane.
__device__ __forceinline__ void gl2lds16(const unsigned short* src,
                                         unsigned short* dst) {
  __builtin_amdgcn_global_load_lds(
      (const __attribute__((address_space(1))) unsigned int*)src,
      (__attribute__((address_space(3))) unsigned int*)dst, 16, 0, 0);
}

// ---------------------------------------------------------------------------
// Weight transpose body: W[k][n] fp32 (stride Nsrc) -> Wt[n_off+n][k] bf16.
// ---------------------------------------------------------------------------
__device__ __forceinline__ void tw_body(
    const float* __restrict__ W, unsigned short* __restrict__ Wt,
    int Nsrc, int Kdst, int n_off, int bx, int by, int tid,
    unsigned short (*Ts)[72]) {
  const int n0 = bx * 64, k0 = by * 64;
  const int c2 = (tid & 31) * 2, rb = tid >> 5;
#pragma unroll
  for (int p = 0; p < 8; ++p) {
    int r = rb + p * 8;
    float2 v = *(const float2*)&W[(size_t)(k0 + r) * Nsrc + n0 + c2];
    Ts[c2][r] = f2bf(v.x);
    Ts[c2 + 1][r] = f2bf(v.y);
  }
  __syncthreads();
  const int n = tid >> 2, kq = (tid & 3) * 16;
  ushort8 w0 = *(const ushort8*)&Ts[n][kq];
  ushort8 w1 = *(const ushort8*)&Ts[n][kq + 8];
  size_t base = (size_t)(n_off + n0 + n) * Kdst + k0 + kq;
  *(ushort8*)&Wt[base] = w0;
  *(ushort8*)&Wt[base + 8] = w1;
}

// ---------------------------------------------------------------------------
// Fused prep: h2b (blocks 0..2047) + wq^T (2048..3071) + wk^T (3072..3327)
// + wv^T (3328..3583) [+ wo^T (3584..4607) when tier2].
// ---------------------------------------------------------------------------
__global__ __launch_bounds__(256) void prep_kernel(
    const float* __restrict__ H, unsigned short* __restrict__ Hb,
    const float* __restrict__ wq, const float* __restrict__ wk,
    const float* __restrict__ wv, unsigned short* __restrict__ WT1,
    const float* __restrict__ wo, unsigned short* __restrict__ WoT) {
  __shared__ unsigned short Ts[64][72];
  const int b = (int)blockIdx.x, tid = threadIdx.x;
  if (b < 2048) {
    int i = (b * 256 + tid) * 8;
    float4 a = *(const float4*)(H + i), c = *(const float4*)(H + i + 4);
    ushort8 r;
    r[0] = f2bf(a.x); r[1] = f2bf(a.y); r[2] = f2bf(a.z); r[3] = f2bf(a.w);
    r[4] = f2bf(c.x); r[5] = f2bf(c.y); r[6] = f2bf(c.z); r[7] = f2bf(c.w);
    *(ushort8*)(Hb + i) = r;
  } else if (b < 3072) {
    int t = b - 2048;
    tw_body(wq, WT1, HIDDIM, HIDDIM, 0, t & 31, t >> 5, tid, Ts);
  } else if (b < 3328) {
    int t = b - 3072;
    tw_body(wk, WT1, 512, HIDDIM, 2048, t & 7, t >> 3, tid, Ts);
  } else if (b < 3584) {
    int t = b - 3328;
    tw_body(wv, WT1, 512, HIDDIM, 2560, t & 7, t >> 3, tid, Ts);
  } else {
    int t = b - 3584;
    tw_body(wo, WoT, HIDDIM, HIDDIM, 0, t & 31, t >> 5, tid, Ts);
  }
}

// ---------------------------------------------------------------------------
// Standalone weight transpose (Wo^T fallback path, runs after attn).
// ---------------------------------------------------------------------------
__global__ __launch_bounds__(256) void transpose_w(
    const float* __restrict__ W, unsigned short* __restrict__ Wt,
    int Nsrc, int Kdst, int n_off) {
  __shared__ unsigned short Ts[64][72];
  tw_body(W, Wt, Nsrc, Kdst, n_off, (int)blockIdx.x, (int)blockIdx.y,
          (int)threadIdx.x, Ts);
}

// ---------------------------------------------------------------------------
// Fused transpose_v (blocks 0..255) + rope (256..767) + maskbits (768).
// ---------------------------------------------------------------------------
__global__ __launch_bounds__(256) void tvrope_kernel(
    unsigned short* __restrict__ Qb, unsigned short* __restrict__ KVb,
    unsigned short* __restrict__ Vt, const int* __restrict__ pos,
    const int* __restrict__ amask, unsigned* __restrict__ mb) {
  __shared__ unsigned short Ts[64][72];
  const int b = (int)blockIdx.x, tid = threadIdx.x;
  if (b < 256) {
    const int c0 = (b & 7) * 64, s0 = (b >> 3) * 64;
    const int sr = tid >> 2, cq = (tid & 3) * 16;
    ushort8 a = *(const ushort8*)&KVb[(size_t)(s0 + sr) * KVROW + 512 + c0 + cq];
    ushort8 c = *(const ushort8*)&KVb[(size_t)(s0 + sr) * KVROW + 512 + c0 + cq + 8];
#pragma unroll
    for (int j = 0; j < 8; ++j) { Ts[cq + j][sr] = a[j]; Ts[cq + 8 + j][sr] = c[j]; }
    __syncthreads();
    const int cc = tid >> 2, sq = (tid & 3) * 16;
    ushort8 w0 = *(const ushort8*)&Ts[cc][sq];
    ushort8 w1 = *(const ushort8*)&Ts[cc][sq + 8];
    *(ushort8*)&Vt[(size_t)(c0 + cc) * S_LEN + s0 + sq] = w0;
    *(ushort8*)&Vt[(size_t)(c0 + cc) * S_LEN + s0 + sq + 8] = w1;
  } else if (b < 768) {
    int idx = (b - 256) * 256 + tid;
    int s = idx >> 6, j = idx & 63;
    float inv = exp2f(-0.2076205059304703f * (float)j);
    float ang = (float)pos[s] * inv;
    float sn, cs;
    __sincosf(ang, &sn, &cs);
    auto rot = [&](unsigned short* base) {
      unsigned* p = (unsigned*)base;
      unsigned v = *p;
      float x0 = bf2f((unsigned short)(v & 0xffff));
      float x1 = bf2f((unsigned short)(v >> 16));
      unsigned r = (unsigned)f2bf(x0 * cs - x1 * sn) |
                   ((unsigned)f2bf(x0 * sn + x1 * cs) << 16);
      *p = r;
    };
#pragma unroll
    for (int hh = 0; hh < NH; ++hh) rot(Qb + (size_t)s * HIDDIM + hh * HD + 2 * j);
#pragma unroll
    for (int hh = 0; hh < NKV; ++hh) rot(KVb + (size_t)s * KVROW + hh * HD + 2 * j);
  } else {
    if (tid < 64) {
      unsigned m = 0;
#pragma unroll
      for (int i = 0; i < 32; ++i) m |= (amask[tid * 32 + i] != 0 ? 1u : 0u) << i;
      mb[tid] = m;
    }
  }
}

// ---------------------------------------------------------------------------
// MFMA GEMM (TN) v3 (unchanged from R13): BM=128, BN=64, BK=64,
// global_load_lds staging, LDS dbuf, one barrier/step, XOR-swizzled tiles.
// ---------------------------------------------------------------------------
template <bool CF>
__global__ __launch_bounds__(256) void gemm_tn(
    const unsigned short* __restrict__ A, const unsigned short* __restrict__ Bt,
    void* __restrict__ C1, void* __restrict__ C2,
    int M, int N, int K, int splitcol, int ld1, int ld2) {
  __shared__ unsigned short As[2][128 * 64];
  __shared__ unsigned short Bs[2][64 * 64];
  const int m0 = blockIdx.y * 128, n0 = blockIdx.x * 64;
  const int tid = threadIdx.x, wid = tid >> 6, lane = tid & 63;
  const int wr = wid >> 1, wc = wid & 1;
  const int lr = lane & 15, lg = lane >> 4;

  f32x4 acc[4][2];
#pragma unroll
  for (int m = 0; m < 4; ++m)
#pragma unroll
    for (int n = 0; n < 2; ++n) acc[m][n] = (f32x4){0.f, 0.f, 0.f, 0.f};

  const int srow = lane >> 3;
  const int scolb = (lane & 7) << 4;
  auto stage = [&](int k0, int b) {
#pragma unroll
    for (int j = 0; j < 4; ++j) {
      int row = wid * 32 + j * 8 + srow;
      int src = (scolb ^ ((row & 7) << 4)) >> 1;
      gl2lds16(A + (size_t)(m0 + row) * K + k0 + src,
               &As[b][(wid * 32 + j * 8) * 64]);
    }
#pragma unroll
    for (int j = 0; j < 2; ++j) {
      int row = wid * 16 + j * 8 + srow;
      int src = (scolb ^ ((row & 7) << 4)) >> 1;
      gl2lds16(Bt + (size_t)(n0 + row) * K + k0 + src,
               &Bs[b][(wid * 16 + j * 8) * 64]);
    }
  };

  stage(0, 0);
  int cur = 0;
  for (int k0 = 0; k0 < K; k0 += 64) {
    __syncthreads();
    if (k0 + 64 < K) stage(k0 + 64, cur ^ 1);
#pragma unroll
    for (int s = 0; s < 2; ++s) {
      short8 af[4], bfv[2];
#pragma unroll
      for (int m = 0; m < 4; ++m) {
        int row = wr * 64 + m * 16 + lr;
        int off = ((s * 64 + lg * 16) ^ ((row & 7) << 4)) >> 1;
        af[m] = *(const short8*)&As[cur][row * 64 + off];
      }
#pragma unroll
      for (int n = 0; n < 2; ++n) {
        int row = wc * 32 + n * 16 + lr;
        int off = ((s * 64 + lg * 16) ^ ((row & 7) << 4)) >> 1;
        bfv[n] = *(const short8*)&Bs[cur][row * 64 + off];
      }
#pragma unroll
      for (int m = 0; m < 4; ++m)
#pragma unroll
        for (int n = 0; n < 2; ++n)
          acc[m][n] = __builtin_amdgcn_mfma_f32_16x16x32_bf16(af[m], bfv[n], acc[m][n], 0, 0, 0);
    }
    cur ^= 1;
  }

#pragma unroll
  for (int m = 0; m < 4; ++m)
#pragma unroll
    for (int n = 0; n < 2; ++n)
#pragma unroll
      for (int r = 0; r < 4; ++r) {
        int row = m0 + wr * 64 + m * 16 + lg * 4 + r;
        int col = n0 + wc * 32 + n * 16 + lr;
        float v = acc[m][n][r];
        if (CF) ((float*)C1)[(size_t)row * ld1 + col] = v;
        else if (col < splitcol) ((unsigned short*)C1)[(size_t)row * ld1 + col] = f2bf(v);
        else ((unsigned short*)C2)[(size_t)row * ld2 + (col - splitcol)] = f2bf(v);
      }
}

// ---------------------------------------------------------------------------
// Flash attention v15: R14/R17 structure + XCD-AWARE 1D GRID. Dispatch index
// d -> XCD d%8 (round-robin heuristic); kvh pinned to XCD pairs
// (kvh = (d&7)>>1) so each XCD's L2 only caches ONE kv-group's K/V/Vt
// (1.5MB) + its Q rows (~2MB) -> L2-resident, stage loads hit L2 not HBM.
// Within-kvh slot order keeps short-chunks-last. Mapping is bijective;
// if the XCD heuristic is wrong this is perf-neutral, never incorrect.
// ---------------------------------------------------------------------------
__global__ __launch_bounds__(256) void attn_kernel(
    const unsigned short* __restrict__ Qb, const unsigned short* __restrict__ KVb,
    const unsigned short* __restrict__ VtG, const unsigned* __restrict__ mbits,
    unsigned short* __restrict__ Ob,
    unsigned short* __restrict__ Opart, float* __restrict__ Lpart, int nsplit) {
  const int d = (int)blockIdx.x;               // 0..1023
  const int kvh = (d & 7) >> 1;                // XCD pair -> kv-group
  const int x = ((d >> 3) << 1) | (d & 1);     // 0..255 within kv-group
  const int qt = 63 - (x >> 2);                // short chunks last
  const int c = x & 3;
  const int nch = (qt >> 4) + 1;
  if (nsplit == 0) { if (c != 0) return; }
  else if (c >= nch) return;
  const int qb = qt * 32;
  int kbeg = 0, kend = qb + 32;
  bool partial = false;
  if (nsplit && nch > 1) {
    kbeg = c * 512;
    kend = min(kend, kbeg + 512);
    partial = true;
  }

  __shared__ unsigned short Klds[2][32 * 128];  // K[key][d], swizzled
  __shared__ unsigned short Vlds[2][128 * 32];  // V^T[d][key], swizzled
  __shared__ unsigned short Plds[4][32][40];    // per-wave P[q32][key]
  const int tid = threadIdx.x, wid = tid >> 6, lane = tid & 63;
  const int lr = lane & 15, lg = lane >> 4;
  const int h = kvh * 4 + wid;                  // wave's head

  short8 qfa[4], qfb[4];
  {
    const unsigned short* qpa = Qb + (size_t)(qb + lr) * HIDDIM + h * HD;
    const unsigned short* qpb = Qb + (size_t)(qb + 16 + lr) * HIDDIM + h * HD;
#pragma unroll
    for (int cc = 0; cc < 4; ++cc) {
      qfa[cc] = *(const short8*)(qpa + cc * 32 + lg * 8);
      qfb[cc] = *(const short8*)(qpb + cc * 32 + lg * 8);
    }
  }
  f32x4 oa[8], ob[8];
#pragma unroll
  for (int cc = 0; cc < 8; ++cc) {
    oa[cc] = (f32x4){0.f, 0.f, 0.f, 0.f};
    ob[cc] = (f32x4){0.f, 0.f, 0.f, 0.f};
  }
  float lsa = 0.f, lsb = 0.f;

  const unsigned short* Vg = VtG + (size_t)(kvh * HD) * S_LEN;

  const int ksr_ = lane >> 4;
  const int kscb = (lane & 15) << 4;
  const int vsr_ = lane >> 2;
  const int vscb = (lane & 3) << 4;

  auto stage = [&](int kt, int b) {
#pragma unroll
    for (int j = 0; j < 2; ++j) {
      int krow = wid * 8 + j * 4 + ksr_;
      int ksrc = (kscb ^ ((krow & 7) << 4)) >> 1;
      gl2lds16(KVb + (size_t)(kt + krow) * KVROW + kvh * HD + ksrc,
               &Klds[b][(wid * 8 + j * 4) * 128]);
      int vrow = wid * 32 + j * 16 + vsr_;
      int vsrc = (vscb ^ ((vrow & 3) << 4)) >> 1;
      gl2lds16(Vg + (size_t)vrow * S_LEN + kt + vsrc,
               &Vlds[b][(wid * 32 + j * 16) * 32]);
    }
  };

  stage(kbeg, 0);

  const int qra = qb + lr, qrb = qb + 16 + lr;
  const float SCALE = 0.08838834764831845f;
  int cur = 0;

  for (int kt = kbeg; kt < kend; kt += 32) {
    __syncthreads();  // drains async stage into buf[cur]
    if (kt + 32 < kend) stage(kt + 32, cur ^ 1);

    f32x4 sa[2], sb[2];
#pragma unroll
    for (int t = 0; t < 2; ++t) {
      sa[t] = (f32x4){0.f, 0.f, 0.f, 0.f};
      sb[t] = (f32x4){0.f, 0.f, 0.f, 0.f};
    }
    const unsigned short* kbase = &Klds[cur][0];
    __builtin_amdgcn_s_setprio(1);
#pragma unroll
    for (int t = 0; t < 2; ++t)
#pragma unroll
      for (int cc = 0; cc < 4; ++cc) {
        short8 kf = *(const short8*)(kbase + ((t * 16 + lr) << 7) +
                                     ((((cc << 6) + (lg << 4)) ^ ((lr & 7) << 4)) >> 1));
        sa[t] = __builtin_amdgcn_mfma_f32_16x16x32_bf16(kf, qfa[cc], sa[t], 0, 0, 0);
        sb[t] = __builtin_amdgcn_mfma_f32_16x16x32_bf16(kf, qfb[cc], sb[t], 0, 0, 0);
      }
    __builtin_amdgcn_s_setprio(0);
    const unsigned mw = mbits[kt >> 5];
    float pa[2][4], pb[2][4];
    if ((kt + 31 <= qb) && (mw == ~0u)) {
#pragma unroll
      for (int t = 0; t < 2; ++t)
#pragma unroll
        for (int r = 0; r < 4; ++r) {
          float va = __expf(sa[t][r] * SCALE - 3.0f);
          float vb = __expf(sb[t][r] * SCALE - 3.0f);
          pa[t][r] = va; lsa += va;
          pb[t][r] = vb; lsb += vb;
        }
    } else {
#pragma unroll
      for (int t = 0; t < 2; ++t)
#pragma unroll
        for (int r = 0; r < 4; ++r) {
          int kk = t * 16 + lg * 4 + r;
          bool okm = (mw >> kk) & 1u;
          float va = __expf((okm && kt + kk <= qra) ? sa[t][r] * SCALE - 3.0f : -1e30f);
          float vb = __expf((okm && kt + kk <= qrb) ? sb[t][r] * SCALE - 3.0f : -1e30f);
          pa[t][r] = va; lsa += va;
          pb[t][r] = vb; lsb += vb;
        }
    }
#pragma unroll
    for (int t = 0; t < 2; ++t) {
      ushort4v pka, pkb;
#pragma unroll
      for (int r = 0; r < 4; ++r) { pka[r] = f2bf(pa[t][r]); pkb[r] = f2bf(pb[t][r]); }
      *(ushort4v*)&Plds[wid][lr][t * 16 + lg * 4] = pka;
      *(ushort4v*)&Plds[wid][16 + lr][t * 16 + lg * 4] = pkb;
    }
    short8 pfa = *(const short8*)&Plds[wid][lr][lg * 8];
    short8 pfb = *(const short8*)&Plds[wid][16 + lr][lg * 8];
    const unsigned short* vbase = &Vlds[cur][0];
    __builtin_amdgcn_s_setprio(1);
#pragma unroll
    for (int cc = 0; cc < 8; ++cc) {
      short8 vf = *(const short8*)(vbase + ((cc * 16 + lr) << 5) +
                                   ((lg ^ (lr & 3)) << 3));
      oa[cc] = __builtin_amdgcn_mfma_f32_16x16x32_bf16(pfa, vf, oa[cc], 0, 0, 0);
      ob[cc] = __builtin_amdgcn_mfma_f32_16x16x32_bf16(pfb, vf, ob[cc], 0, 0, 0);
    }
    __builtin_amdgcn_s_setprio(0);
    cur ^= 1;
  }

  float la = lsa;
  la += __shfl_xor(la, 16, 64);
  la += __shfl_xor(la, 32, 64);
  float lb = lsb;
  lb += __shfl_xor(lb, 16, 64);
  lb += __shfl_xor(lb, 32, 64);

  if (!partial) {
    float lra[4], lrb[4];
#pragma unroll
    for (int r = 0; r < 4; ++r) {
      lra[r] = 1.0f / __shfl(la, lg * 4 + r, 16);
      lrb[r] = 1.0f / __shfl(lb, lg * 4 + r, 16);
    }
#pragma unroll
    for (int cc = 0; cc < 8; ++cc)
#pragma unroll
      for (int r = 0; r < 4; ++r) {
        const int rowa = qb + lg * 4 + r;
        const int rowb = qb + 16 + lg * 4 + r;
        Ob[(size_t)rowa * HIDDIM + h * HD + cc * 16 + lr] = f2bf(oa[cc][r] * lra[r]);
        Ob[(size_t)rowb * HIDDIM + h * HD + cc * 16 + lr] = f2bf(ob[cc][r] * lrb[r]);
      }
  } else {
    const int g = qt >> 4, j = qt & 15;
    const int base = (g == 1) ? 0 : (g == 2) ? 32 : 80;
    const int slot = base + j * nch + c + 144 * kvh;
    if (lg == 0) {
      Lpart[slot * 128 + wid * 32 + lr] = la;
      Lpart[slot * 128 + wid * 32 + 16 + lr] = lb;
    }
#pragma unroll
    for (int cc = 0; cc < 8; ++cc)
#pragma unroll
      for (int r = 0; r < 4; ++r) {
        Opart[(size_t)slot * 16384 + wid * 4096 +
              (lg * 4 + r) * 128 + cc * 16 + lr] = f2bf(oa[cc][r]);
        Opart[(size_t)slot * 16384 + wid * 4096 +
              (16 + lg * 4 + r) * 128 + cc * 16 + lr] = f2bf(ob[cc][r]);
      }
  }
}

// ---------------------------------------------------------------------------
__global__ __launch_bounds__(256) void combine_kernel(
    const unsigned short* __restrict__ Opart, const float* __restrict__ Lpart,
    unsigned short* __restrict__ Ab) {
  const int qt = 16 + (int)blockIdx.x;
  const int kvh = (int)blockIdx.y;
  const int nch = (qt >> 4) + 1;
  const int g = qt >> 4, j = qt & 15;
  const int base = (g == 1) ? 0 : (g == 2) ? 32 : 80;
  const int s0 = base + j * nch + 144 * kvh;
  const int tid = threadIdx.x;
  const int rowid = tid >> 1;
  const int d0 = (tid & 1) * 64;
  float L = 0.f;
  for (int cc = 0; cc < nch; ++cc) L += Lpart[(s0 + cc) * 128 + rowid];
  const float linv = 1.0f / L;
  const int h = kvh * 4 + (rowid >> 5);
  const int row = qt * 32 + (rowid & 31);
  unsigned short* dst = Ab + (size_t)row * HIDDIM + h * HD + d0;
  for (int i = 0; i < 64; i += 8) {
    float acc[8] = {0, 0, 0, 0, 0, 0, 0, 0};
    for (int cc = 0; cc < nch; ++cc) {
      ushort8 v = *(const ushort8*)&Opart[(size_t)(s0 + cc) * 16384 +
                                          rowid * 128 + d0 + i];
#pragma unroll
      for (int k = 0; k < 8; ++k) acc[k] += bf2f(v[k]);
    }
    ushort8 r;
#pragma unroll
    for (int k = 0; k < 8; ++k) r[k] = f2bf(acc[k] * linv);
    *(ushort8*)(dst + i) = r;
  }
}

// ---------------------------------------------------------------------------
extern "C" void kernel_launch(void* const* d_in, const int* in_sizes, int n_in,
                              void* d_out, int out_size, void* d_ws, size_t ws_size,
                              hipStream_t stream) {
  const float* hidden = (const float*)d_in[0];
  const float* wq = (const float*)d_in[1];
  const float* wk = (const float*)d_in[2];
  const float* wv = (const float*)d_in[3];
  const float* wo = (const float*)d_in[4];
  const int* amask = (const int*)d_in[5];
  const int* pos = (const int*)d_in[6];

  unsigned short* Qb = (unsigned short*)d_ws;              // 0      .. 8.39MB
  unsigned short* KVb = Qb + (size_t)S_LEN * HIDDIM;       // 8.39   .. 12.58
  unsigned short* Ab = KVb + (size_t)S_LEN * KVROW;        // 12.58  .. 20.97
  unsigned short* WT1 = Ab + (size_t)S_LEN * HIDDIM;       // 20.97  .. 33.55
  unsigned short* Hb = WT1 + (size_t)QKVN * HIDDIM;        // 33.55  .. 41.94
  float* out = (float*)d_out;

  // Chunked-path extras (aliasing WT1+Hb, dead during attn):
  unsigned short* Opart = WT1;                             // 576 slots x 32KB
  unsigned short* Vt_chunk = WT1 + (size_t)576 * 16384;
  unsigned* mbits_chunk = (unsigned*)((char*)d_ws + 41943040ull);
  float* Lpart = (float*)((char*)d_ws + 41943296ull);
  const size_t need_chunk = 42238208ull;
  // Tier2: separate Wo^T buffer (transposed early inside prep)
  unsigned short* WoT2 = (unsigned short*)((char*)d_ws + 42238208ull);
  const size_t need_tier2 = 42238208ull + 8388608ull;
  // Fallback locations:
  unsigned short* Vt_fb = WT1 + (size_t)HIDDIM * HIDDIM;
  unsigned* mbits_fb = (unsigned*)((char*)d_ws + 31457280ull);

  const int nsplit = (ws_size >= need_chunk) ? 1 : 0;
  const int tier2 = (ws_size >= need_tier2) ? 1 : 0;
  unsigned short* Vt = nsplit ? Vt_chunk : Vt_fb;
  unsigned* mbits = nsplit ? mbits_chunk : mbits_fb;
  unsigned short* WoT = tier2 ? WoT2 : WT1;

  dim3 blk(256);
  // Fused prep: h2b + wq/wk/wv transposes (+ wo^T when tier2)
  prep_kernel<<<tier2 ? 4608 : 3584, blk, 0, stream>>>(
      hidden, Hb, wq, wk, wv, WT1, wo, WoT2);
  // Fused QKV projection: cols<2048 -> Qb, else -> KVb
  gemm_tn<false><<<dim3(QKVN / 64, S_LEN / 128), blk, 0, stream>>>(
      Hb, WT1, Qb, KVb, S_LEN, QKVN, HIDDIM, 2048, HIDDIM, KVROW);
  // Fused V transpose + RoPE + maskbits
  tvrope_kernel<<<769, blk, 0, stream>>>(Qb, KVb, Vt, pos, amask, mbits);
  // Attention: XCD-aware 1D grid (kvh pinned to XCD pairs)
  attn_kernel<<<dim3(1024), blk, 0, stream>>>(
      Qb, KVb, Vt, mbits, Ab, Opart, Lpart, nsplit);
  if (nsplit)
    combine_kernel<<<dim3(48, NKV), blk, 0, stream>>>(Opart, Lpart, Ab);
  // Fallback only: Wo^T late into WT1 (tier2 already did it in prep)
  if (!tier2)
    transpose_w<<<dim3(32, 32), blk, 0, stream>>>(wo, WT1, HIDDIM, HIDDIM, 0);
  // Output projection (fp32 out)
  gemm_tn<true><<<dim3(HIDDIM / 64, S_LEN / 128), blk, 0, stream>>>(
      Ab, WoT, out, nullptr, S_LEN, HIDDIM, HIDDIM, HIDDIM, HIDDIM, 0);
}